// Round 14
// baseline (313.232 us; speedup 1.0000x reference)
//
#include <hip/hip_runtime.h>
#include <hip/hip_bf16.h>
#include <hip/hip_cooperative_groups.h>
#include <math.h>

namespace cg = cooperative_groups;

// MAB: q=QWq^T+bq; k=KWk^T+bk; v=KWv^T+bv; per-head softmax(qk^T/16)v + q-residual;
// LN0; +relu(GEMM Wo); LN1.  B=4, N=2048, D=256, H=4, Dh=64.
// Round 14: cooperative mega-kernel, 256 blocks x 512 thr (co-resident even at
// 1 block/CU), 2 units/phase/block. __threadfence() around grid.sync() for
// cross-XCD visibility. Launch error -> fall back to validated 3-kernel path.
// ws (8 MB): [0,4MB) k bf16 [8192][256]; [4,8MB) v_t bf16 [16][64][2048].

typedef __attribute__((ext_vector_type(8))) short bf16x8;
typedef __attribute__((ext_vector_type(4))) float f32x4;

static __device__ __forceinline__ unsigned short f2bf(float x) {
  return __bfloat16_as_ushort(__float2bfloat16(x));
}
static __device__ __forceinline__ int pk2(float lo, float hi) {
  return (int)((unsigned)f2bf(lo) | ((unsigned)f2bf(hi) << 16));
}
static __device__ __forceinline__ float exp2_fast(float x) {
  float r; asm("v_exp_f32 %0, %1" : "=v"(r) : "v"(x)); return r;
}

#define SWZ(row, col) ((col) ^ (((row) & 7) << 3))

typedef unsigned short tile64_t[64][64];

// ===========================================================================
// Cooperative mega-kernel: 256 blocks x 512 threads, 64KB dynamic LDS.
// ===========================================================================
__global__ __launch_bounds__(512) void mab_mega(
    const float* __restrict__ Q, const float* __restrict__ K,
    const float* __restrict__ Wq, const float* __restrict__ bq,
    const float* __restrict__ Wk, const float* __restrict__ bk,
    const float* __restrict__ Wv, const float* __restrict__ bv,
    const float* __restrict__ Wo, const float* __restrict__ bo,
    const float* __restrict__ g0v, const float* __restrict__ b0v,
    const float* __restrict__ g1v, const float* __restrict__ b1v,
    float* __restrict__ out, unsigned short* __restrict__ kbf,
    unsigned short* __restrict__ vtb)
{
  extern __shared__ __align__(16) char smem[];
  cg::grid_group grid = cg::this_grid();

  const int tid = threadIdx.x;
  const int wid = tid >> 6;        // 0..7
  const int lane = tid & 63;
  const int l15 = lane & 15;
  const int g = lane >> 4;

  // ======================= Phase A: projections ===========================
  // unit p in {bid, bid+256} -> tile (bn = p&3, bm = p>>2); z = 0(q),1(k),2(v)
  // 8 waves as 2x4: wave (wr,wc) computes rows [wr*32,+32) x cols [wc*16,+16).
  {
    unsigned short (*Ab)[64] = (unsigned short(*)[64])smem;            // 8 KB
    unsigned short (*Wb)[64] = (unsigned short(*)[64])(smem + 8192);   // 8 KB
    const int wr = wid >> 2, wc = wid & 3;
    const int srow = tid >> 3, sch = (tid & 7) * 8;
    const int sdst = SWZ(srow, sch);

    for (int u = 0; u < 2; ++u) {
      const int p = blockIdx.x + u * 256;
      const int bn = p & 3, bm = p >> 2;
      for (int z = 0; z < 3; ++z) {
        const float* A    = (z == 0) ? Q  : K;
        const float* W    = (z == 0) ? Wq : ((z == 1) ? Wk : Wv);
        const float* bias = (z == 0) ? bq : ((z == 1) ? bk : bv);
        const float* Ablk = A + (size_t)bm * 64 * 256;
        const float* Wblk = W + (size_t)bn * 64 * 256;

        f32x4 acc[2];
        #pragma unroll
        for (int mi = 0; mi < 2; ++mi)
          #pragma unroll
          for (int r = 0; r < 4; ++r) acc[mi][r] = 0.f;

        for (int k0 = 0; k0 < 256; k0 += 64) {
          if (u + z + k0) __syncthreads();
          {
            const float* ap = Ablk + (size_t)srow*256 + k0 + sch;
            float4 a0 = *(const float4*)ap, a1 = *(const float4*)(ap + 4);
            int4 pa = { pk2(a0.x,a0.y), pk2(a0.z,a0.w), pk2(a1.x,a1.y), pk2(a1.z,a1.w) };
            *(int4*)&Ab[srow][sdst] = pa;
            const float* wp = Wblk + (size_t)srow*256 + k0 + sch;
            float4 w0 = *(const float4*)wp, w1 = *(const float4*)(wp + 4);
            int4 pw = { pk2(w0.x,w0.y), pk2(w0.z,w0.w), pk2(w1.x,w1.y), pk2(w1.z,w1.w) };
            *(int4*)&Wb[srow][sdst] = pw;
          }
          __syncthreads();
          const unsigned short (*Ta)[64] = (z == 2) ? Wb : Ab;
          const unsigned short (*Tb)[64] = (z == 2) ? Ab : Wb;
          __builtin_amdgcn_s_setprio(1);
          #pragma unroll
          for (int kc = 0; kc < 64; kc += 32) {
            const int rb = wc*16 + l15;
            bf16x8 bfv = *(const bf16x8*)&Tb[rb][SWZ(rb, kc + g*8)];
            #pragma unroll
            for (int mi = 0; mi < 2; ++mi) {
              const int ra = wr*32 + mi*16 + l15;
              bf16x8 af = *(const bf16x8*)&Ta[ra][SWZ(ra, kc + g*8)];
              acc[mi] = __builtin_amdgcn_mfma_f32_16x16x32_bf16(af, bfv, acc[mi], 0, 0, 0);
            }
          }
          __builtin_amdgcn_s_setprio(0);
        }

        if (z == 2) {
          const int bvb = bm >> 5;
          const size_t n0 = (size_t)(bm & 31)*64 + wc*16 + l15;
          #pragma unroll
          for (int mi = 0; mi < 2; ++mi)
            #pragma unroll
            for (int r = 0; r < 4; ++r) {
              int d = wr*32 + mi*16 + g*4 + r;
              float c = acc[mi][r] + bias[bn*64 + d];
              vtb[((size_t)(bvb*4 + bn)*64 + d)*2048 + n0] = f2bf(c);
            }
        } else {
          const int col = bn*64 + wc*16 + l15;
          const float bcol = bias[col];
          #pragma unroll
          for (int mi = 0; mi < 2; ++mi)
            #pragma unroll
            for (int r = 0; r < 4; ++r) {
              int row = bm*64 + wr*32 + mi*16 + g*4 + r;
              float c = acc[mi][r] + bcol;
              if (z == 0) out[(size_t)row*256 + col] = c;
              else        kbf[(size_t)row*256 + col] = f2bf(c);
            }
        }
      }
    }
  }

  __threadfence();
  grid.sync();
  __threadfence();

  // ======================= Phase B: attention (v6) ========================
  {
    tile64_t* Ks = (tile64_t*)smem;             // [grp*2+buf], 32 KB
    tile64_t* Vt = (tile64_t*)(smem + 32768);   // [grp*2+buf], 32 KB
    const int grp = wid >> 2;
    const int w4  = wid & 3;

    for (int u = 0; u < 2; ++u) {
      __syncthreads();                          // LDS free from prior use
      const int lin = blockIdx.x + u * 256;     // preserves lin&7 (XCD bucket)
      const int xcd = lin & 7, idx = lin >> 3;
      const int bh = xcd * 2 + (idx >> 5);
      const int qb = idx & 31;
      const int b = bh >> 2, h = bh & 3;

      const float qscale = 0.0625f * 1.44269504089f;
      bf16x8 qf[2];
      {
        const float* qp = out + ((size_t)(b*2048 + qb*64 + w4*16 + l15))*256 + h*64;
        #pragma unroll
        for (int ds_ = 0; ds_ < 2; ++ds_) {
          union { bf16x8 v; unsigned short s[8]; } tmp;
          #pragma unroll
          for (int j = 0; j < 8; ++j) tmp.s[j] = f2bf(qp[ds_*32 + g*8 + j] * qscale);
          qf[ds_] = tmp.v;
        }
      }

      const int gt = tid & 255;
      const int sr = gt >> 2, sc = (gt & 3) * 16;
      const int c0 = SWZ(sr, sc), c1 = SWZ(sr, sc + 8);
      const unsigned short* kgp = kbf + ((size_t)(b*2048 + grp*1024 + sr))*256 + h*64 + sc;
      const unsigned short* vgp = vtb + ((size_t)bh*64 + sr)*2048 + grp*1024 + sc;

      f32x4 oa[4];
      #pragma unroll
      for (int mt = 0; mt < 4; ++mt)
        #pragma unroll
        for (int r = 0; r < 4; ++r) oa[mt][r] = 0.f;
      float l_ = 0.f;

      {
        int4 k0_ = *(const int4*)kgp, k1_ = *(const int4*)(kgp + 8);
        int4 v0_ = *(const int4*)vgp, v1_ = *(const int4*)(vgp + 8);
        *(int4*)&Ks[grp*2+0][sr][c0] = k0_;  *(int4*)&Ks[grp*2+0][sr][c1] = k1_;
        *(int4*)&Vt[grp*2+0][sr][c0] = v0_;  *(int4*)&Vt[grp*2+0][sr][c1] = v1_;
      }
      int4 kA0 = *(const int4*)(kgp + (size_t)64*256);
      int4 kA1 = *(const int4*)(kgp + (size_t)64*256 + 8);
      int4 vA0 = *(const int4*)(vgp + 64);
      int4 vA1 = *(const int4*)(vgp + 64 + 8);
      __syncthreads();

      for (int kt = 0; kt < 16; ++kt) {
        const int cur = kt & 1;
        const tile64_t& Kc = Ks[grp*2 + cur];
        const tile64_t& Vc = Vt[grp*2 + cur];

        f32x4 sa[4];
        #pragma unroll
        for (int mt = 0; mt < 4; ++mt)
          #pragma unroll
          for (int r = 0; r < 4; ++r) sa[mt][r] = 0.f;
        __builtin_amdgcn_s_setprio(1);
        #pragma unroll
        for (int ds_ = 0; ds_ < 2; ++ds_) {
          #pragma unroll
          for (int mt = 0; mt < 4; ++mt) {
            bf16x8 af = *(const bf16x8*)&Kc[mt*16 + l15][SWZ(l15, ds_*32 + g*8)];
            sa[mt] = __builtin_amdgcn_mfma_f32_16x16x32_bf16(af, qf[ds_], sa[mt], 0, 0, 0);
          }
        }
        __builtin_amdgcn_s_setprio(0);

        float ps = 0.f;
        unsigned pk01[4], pk23[4];
        #pragma unroll
        for (int mt = 0; mt < 4; ++mt) {
          float p0 = exp2_fast(sa[mt][0]);
          float p1 = exp2_fast(sa[mt][1]);
          float p2 = exp2_fast(sa[mt][2]);
          float p3 = exp2_fast(sa[mt][3]);
          ps += (p0 + p1) + (p2 + p3);
          pk01[mt] = (unsigned)pk2(p0, p1);
          pk23[mt] = (unsigned)pk2(p2, p3);
        }
        ps += __shfl_xor(ps, 16, 64);
        ps += __shfl_xor(ps, 32, 64);
        l_ += ps;

        __builtin_amdgcn_s_setprio(1);
        #pragma unroll
        for (int ks_ = 0; ks_ < 2; ++ks_) {
          unsigned a0 = pk01[2*ks_], b0 = pk01[2*ks_ + 1];
          unsigned a1 = pk23[2*ks_], b1 = pk23[2*ks_ + 1];
          asm volatile("v_permlane32_swap_b32 %0, %1" : "+v"(a0), "+v"(b0));
          asm volatile("v_permlane16_swap_b32 %0, %1" : "+v"(a0), "+v"(b0));
          asm volatile("v_permlane32_swap_b32 %0, %1" : "+v"(a1), "+v"(b1));
          asm volatile("v_permlane16_swap_b32 %0, %1" : "+v"(a1), "+v"(b1));
          int4 pw = { (int)a0, (int)a1, (int)b0, (int)b1 };
          bf16x8 pf = __builtin_bit_cast(bf16x8, pw);
          #pragma unroll
          for (int mt = 0; mt < 4; ++mt) {
            bf16x8 vf = *(const bf16x8*)&Vc[mt*16 + l15][SWZ(l15, ks_*32 + g*8)];
            oa[mt] = __builtin_amdgcn_mfma_f32_16x16x32_bf16(vf, pf, oa[mt], 0, 0, 0);
          }
        }
        __builtin_amdgcn_s_setprio(0);

        if (kt < 15) {
          *(int4*)&Ks[grp*2+(cur^1)][sr][c0] = kA0;
          *(int4*)&Ks[grp*2+(cur^1)][sr][c1] = kA1;
          *(int4*)&Vt[grp*2+(cur^1)][sr][c0] = vA0;
          *(int4*)&Vt[grp*2+(cur^1)][sr][c1] = vA1;
          if (kt < 14) {
            const unsigned short* kn = kgp + (size_t)(kt + 2) * 64 * 256;
            const unsigned short* vn = vgp + (kt + 2) * 64;
            kA0 = *(const int4*)kn;  kA1 = *(const int4*)(kn + 8);
            vA0 = *(const int4*)vn;  vA1 = *(const int4*)(vn + 8);
          }
        }
        __syncthreads();
      }

      float* cob = (float*)smem;
      float* cml = (float*)(smem + 32768);
      const int ci = w4*64 + lane;
      if (grp == 1) {
        #pragma unroll
        for (int mt = 0; mt < 4; ++mt)
          #pragma unroll
          for (int r = 0; r < 4; ++r) cob[(mt*4 + r)*256 + ci] = oa[mt][r];
        cml[ci] = l_;
      }
      __syncthreads();
      if (grp == 0) {
        float linv = 1.0f / (l_ + cml[ci]);
        float* op = out + ((size_t)(b*2048 + qb*64 + w4*16 + l15))*256 + h*64;
        #pragma unroll
        for (int mt = 0; mt < 4; ++mt) {
          int dbase = mt*16 + g*4;
          float4 qv = *(const float4*)(op + dbase);
          float4 st;
          st.x = qv.x + (oa[mt][0] + cob[(mt*4+0)*256 + ci]) * linv;
          st.y = qv.y + (oa[mt][1] + cob[(mt*4+1)*256 + ci]) * linv;
          st.z = qv.z + (oa[mt][2] + cob[(mt*4+2)*256 + ci]) * linv;
          st.w = qv.w + (oa[mt][3] + cob[(mt*4+3)*256 + ci]) * linv;
          *(float4*)(op + dbase) = st;
        }
      }
    }
  }

  __threadfence();
  grid.sync();
  __threadfence();

  // ============ Phase C: LN0 + res+relu(GEMM Wo) + LN1, in-place ==========
  {
    unsigned short (*As)[256] = (unsigned short(*)[256])smem;          // 8 KB
    float* mu_ = (float*)(smem + 8192);
    float* rs_ = (float*)(smem + 8320);
    unsigned short (*Ws)[64] = (unsigned short(*)[64])(smem + 16384);  // 32 KB
    float* P = (float*)(smem + 16384);                                 // 16 KB reuse
    const int w = wid;
    const float* x = out;

    for (int u = 0; u < 2; ++u) {
      __syncthreads();
      const int r0 = (blockIdx.x + u * 256) * 16;

      {  // LN0 on 16 rows (2 rows/wave) -> As bf16 + stats
        float4 g4 = *(const float4*)(g0v + lane*4);
        float4 b4 = *(const float4*)(b0v + lane*4);
        #pragma unroll
        for (int rr = 0; rr < 2; ++rr) {
          int m = w*2 + rr;
          const float* xr = x + (size_t)(r0 + m) * 256;
          float4 v = *(const float4*)(xr + lane*4);
          float s = v.x + v.y + v.z + v.w;
          #pragma unroll
          for (int mk = 1; mk <= 32; mk <<= 1) s += __shfl_xor(s, mk, 64);
          float mu = s * (1.0f/256.0f);
          float dx = v.x-mu, dy = v.y-mu, dz = v.z-mu, dw = v.w-mu;
          float qq = dx*dx + dy*dy + dz*dz + dw*dw;
          #pragma unroll
          for (int mk = 1; mk <= 32; mk <<= 1) qq += __shfl_xor(qq, mk, 64);
          float rstd = rsqrtf(qq * (1.0f/256.0f) + 1e-5f);
          if (lane == 0) { mu_[m] = mu; rs_[m] = rstd; }
          float nx = dx*rstd*g4.x + b4.x;
          float ny = dy*rstd*g4.y + b4.y;
          float nz = dz*rstd*g4.z + b4.z;
          float nw = dw*rstd*g4.w + b4.w;
          int2 pv = { pk2(nx, ny), pk2(nz, nw) };
          *(int2*)&As[m][SWZ(m, lane*4)] = pv;
        }
      }
      __syncthreads();

      const int e0 = w * 32;
      f32x4 acc4[2];
      #pragma unroll
      for (int j = 0; j < 2; ++j)
        #pragma unroll
        for (int r = 0; r < 4; ++r) acc4[j][r] = 0.f;

      for (int k0 = 0; k0 < 256; k0 += 64) {
        if (k0) __syncthreads();
        {
          const int ch = tid & 7;
          const int er = tid >> 3;
          #pragma unroll
          for (int p = 0; p < 4; ++p) {
            int e = p*64 + er;
            const float* wp = Wo + (size_t)e*256 + k0 + ch*8;
            float4 u0 = *(const float4*)wp;
            float4 u1 = *(const float4*)(wp + 4);
            int4 pk = { pk2(u0.x,u0.y), pk2(u0.z,u0.w), pk2(u1.x,u1.y), pk2(u1.z,u1.w) };
            *(int4*)&Ws[e][SWZ(e, ch*8)] = pk;
          }
        }
        __syncthreads();
        __builtin_amdgcn_s_setprio(1);
        #pragma unroll
        for (int ds_ = 0; ds_ < 2; ++ds_) {
          bf16x8 af = *(const bf16x8*)&As[l15][SWZ(l15, k0 + ds_*32 + g*8)];
          #pragma unroll
          for (int j = 0; j < 2; ++j) {
            int er = e0 + j*16 + l15;
            bf16x8 bfv = *(const bf16x8*)&Ws[er][SWZ(er, ds_*32 + g*8)];
            acc4[j] = __builtin_amdgcn_mfma_f32_16x16x32_bf16(af, bfv, acc4[j], 0, 0, 0);
          }
        }
        __builtin_amdgcn_s_setprio(0);
      }
      __syncthreads();   // Ws reads done; reuse as P

      #pragma unroll
      for (int j = 0; j < 2; ++j) {
        int e = e0 + j*16 + l15;
        float bov = bo[e], g0e = g0v[e], b0e = b0v[e];
        #pragma unroll
        for (int r = 0; r < 4; ++r) {
          int m = g*4 + r;
          float xv = x[(size_t)(r0 + m)*256 + e];
          float resv = (xv - mu_[m]) * rs_[m] * g0e + b0e;
          float val = acc4[j][r] + bov;
          P[m*256 + e] = resv + fmaxf(val, 0.f);
        }
      }
      __syncthreads();

      {  // LN1 (2 rows/wave) -> out
        float4 g4 = *(const float4*)(g1v + lane*4);
        float4 b4 = *(const float4*)(b1v + lane*4);
        #pragma unroll
        for (int rr = 0; rr < 2; ++rr) {
          int m = w*2 + rr;
          float4 v = *(const float4*)&P[m*256 + lane*4];
          float s = v.x + v.y + v.z + v.w;
          #pragma unroll
          for (int mk = 1; mk <= 32; mk <<= 1) s += __shfl_xor(s, mk, 64);
          float mu = s * (1.0f/256.0f);
          float dx = v.x-mu, dy = v.y-mu, dz = v.z-mu, dw = v.w-mu;
          float qq = dx*dx + dy*dy + dz*dz + dw*dw;
          #pragma unroll
          for (int mk = 1; mk <= 32; mk <<= 1) qq += __shfl_xor(qq, mk, 64);
          float rstd = rsqrtf(qq * (1.0f/256.0f) + 1e-5f);
          float4 o;
          o.x = dx*rstd*g4.x + b4.x; o.y = dy*rstd*g4.y + b4.y;
          o.z = dz*rstd*g4.z + b4.z; o.w = dw*rstd*g4.w + b4.w;
          *(float4*)(out + (size_t)(r0 + m)*256 + lane*4) = o;
        }
      }
    }
  }
}

// ===========================================================================
// Fallback path: validated round-9 kernels (3 dispatches).
// ===========================================================================
__global__ __launch_bounds__(256, 2) void proj_kernel(
    const float* __restrict__ Q, const float* __restrict__ K,
    const float* __restrict__ Wq, const float* __restrict__ bq,
    const float* __restrict__ Wk, const float* __restrict__ bk,
    const float* __restrict__ Wv, const float* __restrict__ bv,
    float* __restrict__ qout, unsigned short* __restrict__ kbf,
    unsigned short* __restrict__ vtb)
{
  __shared__ __align__(16) unsigned short Ab[64][64];
  __shared__ __align__(16) unsigned short Wb[64][64];
  const int tid = threadIdx.x;
  const int z = blockIdx.z;
  const int bn = blockIdx.x, bm = blockIdx.y;

  const float* A    = (z == 0) ? Q  : K;
  const float* W    = (z == 0) ? Wq : ((z == 1) ? Wk : Wv);
  const float* bias = (z == 0) ? bq : ((z == 1) ? bk : bv);

  const int wid = tid >> 6, lane = tid & 63;
  const int l15 = lane & 15, g = lane >> 4;
  const int wr = wid >> 1, wc = wid & 1;
  const float* Ablk = A + (size_t)bm * 64 * 256;
  const float* Wblk = W + (size_t)bn * 64 * 256;

  const int sr = tid >> 2, sc = (tid & 3) * 16;
  const int c0 = SWZ(sr, sc), c1 = SWZ(sr, sc + 8);

  f32x4 acc[2][2];
  #pragma unroll
  for (int i = 0; i < 2; ++i)
    #pragma unroll
    for (int j = 0; j < 2; ++j)
      #pragma unroll
      for (int r = 0; r < 4; ++r) acc[i][j][r] = 0.f;

  float4 aR[4], wR[4];
  #pragma unroll
  for (int u = 0; u < 4; ++u) {
    aR[u] = *(const float4*)(Ablk + (size_t)sr*256 + sc + u*4);
    wR[u] = *(const float4*)(Wblk + (size_t)sr*256 + sc + u*4);
  }

  for (int k0 = 0; k0 < 256; k0 += 64) {
    if (k0) __syncthreads();
    int4 pa0 = { pk2(aR[0].x,aR[0].y), pk2(aR[0].z,aR[0].w),
                 pk2(aR[1].x,aR[1].y), pk2(aR[1].z,aR[1].w) };
    int4 pa1 = { pk2(aR[2].x,aR[2].y), pk2(aR[2].z,aR[2].w),
                 pk2(aR[3].x,aR[3].y), pk2(aR[3].z,aR[3].w) };
    int4 pw0 = { pk2(wR[0].x,wR[0].y), pk2(wR[0].z,wR[0].w),
                 pk2(wR[1].x,wR[1].y), pk2(wR[1].z,wR[1].w) };
    int4 pw1 = { pk2(wR[2].x,wR[2].y), pk2(wR[2].z,wR[2].w),
                 pk2(wR[3].x,wR[3].y), pk2(wR[3].z,wR[3].w) };
    *(int4*)&Ab[sr][c0] = pa0;  *(int4*)&Ab[sr][c1] = pa1;
    *(int4*)&Wb[sr][c0] = pw0;  *(int4*)&Wb[sr][c1] = pw1;
    __syncthreads();
    if (k0 < 192) {
      #pragma unroll
      for (int u = 0; u < 4; ++u) {
        aR[u] = *(const float4*)(Ablk + (size_t)sr*256 + (k0+64) + sc + u*4);
        wR[u] = *(const float4*)(Wblk + (size_t)sr*256 + (k0+64) + sc + u*4);
      }
    }
    const unsigned short (*Ta)[64] = (z == 2) ? Wb : Ab;
    const unsigned short (*Tb)[64] = (z == 2) ? Ab : Wb;
    __builtin_amdgcn_s_setprio(1);
    #pragma unroll
    for (int kc = 0; kc < 64; kc += 32) {
      bf16x8 af[2], bf_[2];
      #pragma unroll
      for (int i = 0; i < 2; ++i) {
        int ra = wr*32 + i*16 + l15;
        int rb = wc*32 + i*16 + l15;
        af[i]  = *(const bf16x8*)&Ta[ra][SWZ(ra, kc + g*8)];
        bf_[i] = *(const bf16x8*)&Tb[rb][SWZ(rb, kc + g*8)];
      }
      #pragma unroll
      for (int i = 0; i < 2; ++i)
        #pragma unroll
        for (int j = 0; j < 2; ++j)
          acc[i][j] = __builtin_amdgcn_mfma_f32_16x16x32_bf16(af[i], bf_[j], acc[i][j], 0, 0, 0);
    }
    __builtin_amdgcn_s_setprio(0);
  }

  if (z == 2) {
    const int bvb = bm >> 5;
    const int n0 = (bm & 31) * 64 + wc*32;
    #pragma unroll
    for (int di = 0; di < 2; ++di)
      #pragma unroll
      for (int r = 0; r < 4; ++r) {
        int d = wr*32 + di*16 + g*4 + r;
        float bvs = bias[bn*64 + d];
        #pragma unroll
        for (int ni = 0; ni < 2; ++ni) {
          float c = acc[di][ni][r] + bvs;
          vtb[((size_t)(bvb*4 + bn)*64 + d)*2048 + n0 + ni*16 + l15] = f2bf(c);
        }
      }
    return;
  }

  const int gm = bm*64 + wr*32, ge = bn*64 + wc*32;
  float bv0 = bias[ge + l15], bv1 = bias[ge + 16 + l15];
  #pragma unroll
  for (int mi = 0; mi < 2; ++mi)
    #pragma unroll
    for (int r = 0; r < 4; ++r) {
      int row = gm + mi*16 + g*4 + r;
      #pragma unroll
      for (int ei = 0; ei < 2; ++ei) {
        float c = acc[mi][ei][r] + (ei ? bv1 : bv0);
        if (z == 0) qout[(size_t)row*256 + ge + ei*16 + l15] = c;
        else        kbf [(size_t)row*256 + ge + ei*16 + l15] = f2bf(c);
      }
    }
}

__global__ __launch_bounds__(512, 4) void attn_mfma6(
    const float* __restrict__ q,
    const unsigned short* __restrict__ kb,
    const unsigned short* __restrict__ vt,
    float* __restrict__ o)
{
  extern __shared__ __align__(16) char smem_dyn[];
  tile64_t* Ks = (tile64_t*)smem_dyn;
  tile64_t* Vt = (tile64_t*)(smem_dyn + 32768);

  const int tid = threadIdx.x;
  const int wid = tid >> 6;
  const int grp = wid >> 2;
  const int w4  = wid & 3;
  const int lane = tid & 63;
  const int l15 = lane & 15;
  const int g = lane >> 4;
  const int lin = blockIdx.x;
  const int xcd = lin & 7, idx = lin >> 3;
  const int bh = xcd * 2 + (idx >> 5);
  const int qb = idx & 31;
  const int b = bh >> 2, h = bh & 3;

  const float qscale = 0.0625f * 1.44269504089f;
  bf16x8 qf[2];
  {
    const float* qp = q + ((size_t)(b*2048 + qb*64 + w4*16 + l15))*256 + h*64;
    #pragma unroll
    for (int ds_ = 0; ds_ < 2; ++ds_) {
      union { bf16x8 v; unsigned short s[8]; } tmp;
      #pragma unroll
      for (int j = 0; j < 8; ++j) tmp.s[j] = f2bf(qp[ds_*32 + g*8 + j] * qscale);
      qf[ds_] = tmp.v;
    }
  }

  const int gt = tid & 255;
  const int sr = gt >> 2, sc = (gt & 3) * 16;
  const int c0 = SWZ(sr, sc), c1 = SWZ(sr, sc + 8);
  const unsigned short* kgp = kb + ((size_t)(b*2048 + grp*1024 + sr))*256 + h*64 + sc;
  const unsigned short* vgp = vt + ((size_t)bh*64 + sr)*2048 + grp*1024 + sc;

  f32x4 oa[4];
  #pragma unroll
  for (int mt = 0; mt < 4; ++mt)
    #pragma unroll
    for (int r = 0; r < 4; ++r) oa[mt][r] = 0.f;
  float l_ = 0.f;

  {
    int4 k0_ = *(const int4*)kgp, k1_ = *(const int4*)(kgp + 8);
    int4 v0_ = *(const int4*)vgp, v1_ = *(const int4*)(vgp + 8);
    *(int4*)&Ks[grp*2+0][sr][c0] = k0_;  *(int4*)&Ks[grp*2+0][sr][c1] = k1_;
    *(int4*)&Vt[grp*2+0][sr][c0] = v0_;  *(int4*)&Vt[grp*2+0][sr][c1] = v1_;
  }
  int4 kA0 = *(const int4*)(kgp + (size_t)64*256);
  int4 kA1 = *(const int4*)(kgp + (size_t)64*256 + 8);
  int4 vA0 = *(const int4*)(vgp + 64);
  int4 vA1 = *(const int4*)(vgp + 64 + 8);
  __syncthreads();

  for (int kt = 0; kt < 16; ++kt) {
    const int cur = kt & 1;
    const tile64_t& Kc = Ks[grp*2 + cur];
    const tile64_t& Vc = Vt[grp*2 + cur];

    f32x4 sa[4];
    #pragma unroll
    for (int mt = 0; mt < 4; ++mt)
      #pragma unroll
      for (int r = 0; r < 4; ++r) sa[mt][r] = 0.f;
    __builtin_amdgcn_s_setprio(1);
    #pragma unroll
    for (int ds_ = 0; ds_ < 2; ++ds_) {
      #pragma unroll
      for (int mt = 0; mt < 4; ++mt) {
        bf16x8 af = *(const bf16x8*)&Kc[mt*16 + l15][SWZ(l15, ds_*32 + g*8)];
        sa[mt] = __builtin_amdgcn_mfma_f32_16x16x32_bf16(af, qf[ds_], sa[mt], 0, 0, 0);
      }
    }
    __builtin_amdgcn_s_setprio(0);

    float ps = 0.f;
    unsigned pk01[4], pk23[4];
    #pragma unroll
    for (int mt = 0; mt < 4; ++mt) {
      float p0 = exp2_fast(sa[mt][0]);
      float p1 = exp2_fast(sa[mt][1]);
      float p2 = exp2_fast(sa[mt][2]);
      float p3 = exp2_fast(sa[mt][3]);
      ps += (p0 + p1) + (p2 + p3);
      pk01[mt] = (unsigned)pk2(p0, p1);
      pk23[mt] = (unsigned)pk2(p2, p3);
    }
    ps += __shfl_xor(ps, 16, 64);
    ps += __shfl_xor(ps, 32, 64);
    l_ += ps;

    __builtin_amdgcn_s_setprio(1);
    #pragma unroll
    for (int ks_ = 0; ks_ < 2; ++ks_) {
      unsigned a0 = pk01[2*ks_], b0 = pk01[2*ks_ + 1];
      unsigned a1 = pk23[2*ks_], b1 = pk23[2*ks_ + 1];
      asm volatile("v_permlane32_swap_b32 %0, %1" : "+v"(a0), "+v"(b0));
      asm volatile("v_permlane16_swap_b32 %0, %1" : "+v"(a0), "+v"(b0));
      asm volatile("v_permlane32_swap_b32 %0, %1" : "+v"(a1), "+v"(b1));
      asm volatile("v_permlane16_swap_b32 %0, %1" : "+v"(a1), "+v"(b1));
      int4 pw = { (int)a0, (int)a1, (int)b0, (int)b1 };
      bf16x8 pf = __builtin_bit_cast(bf16x8, pw);
      #pragma unroll
      for (int mt = 0; mt < 4; ++mt) {
        bf16x8 vf = *(const bf16x8*)&Vc[mt*16 + l15][SWZ(l15, ks_*32 + g*8)];
        oa[mt] = __builtin_amdgcn_mfma_f32_16x16x32_bf16(vf, pf, oa[mt], 0, 0, 0);
      }
    }
    __builtin_amdgcn_s_setprio(0);

    if (kt < 15) {
      *(int4*)&Ks[grp*2+(cur^1)][sr][c0] = kA0;
      *(int4*)&Ks[grp*2+(cur^1)][sr][c1] = kA1;
      *(int4*)&Vt[grp*2+(cur^1)][sr][c0] = vA0;
      *(int4*)&Vt[grp*2+(cur^1)][sr][c1] = vA1;
      if (kt < 14) {
        const unsigned short* kn = kgp + (size_t)(kt + 2) * 64 * 256;
        const unsigned short* vn = vgp + (kt + 2) * 64;
        kA0 = *(const int4*)kn;  kA1 = *(const int4*)(kn + 8);
        vA0 = *(const int4*)vn;  vA1 = *(const int4*)(vn + 8);
      }
    }
    __syncthreads();
  }

  float* cob = (float*)smem_dyn;
  float* cml = (float*)(smem_dyn + 32768);
  const int ci = w4*64 + lane;
  if (grp == 1) {
    #pragma unroll
    for (int mt = 0; mt < 4; ++mt)
      #pragma unroll
      for (int r = 0; r < 4; ++r) cob[(mt*4 + r)*256 + ci] = oa[mt][r];
    cml[ci] = l_;
  }
  __syncthreads();
  if (grp == 0) {
    float linv = 1.0f / (l_ + cml[ci]);
    float* op = o + ((size_t)(b*2048 + qb*64 + w4*16 + l15))*256 + h*64;
    #pragma unroll
    for (int mt = 0; mt < 4; ++mt) {
      int dbase = mt*16 + g*4;
      float4 qv = *(const float4*)(op + dbase);
      float4 st;
      st.x = qv.x + (oa[mt][0] + cob[(mt*4+0)*256 + ci]) * linv;
      st.y = qv.y + (oa[mt][1] + cob[(mt*4+1)*256 + ci]) * linv;
      st.z = qv.z + (oa[mt][2] + cob[(mt*4+2)*256 + ci]) * linv;
      st.w = qv.w + (oa[mt][3] + cob[(mt*4+3)*256 + ci]) * linv;
      *(float4*)(op + dbase) = st;
    }
  }
}

__global__ __launch_bounds__(512) void fused_out(
    const float* __restrict__ x, const float* __restrict__ Wo,
    const float* __restrict__ bo,
    const float* __restrict__ g0v, const float* __restrict__ b0v,
    const float* __restrict__ g1v, const float* __restrict__ b1v,
    float* __restrict__ y)
{
  __shared__ __align__(16) unsigned short As[32][256];
  __shared__ __align__(16) unsigned short Ws[256][64];
  __shared__ float mu_[32], rs_[32];
  float* P = (float*)&Ws[0][0];

  const int tid = threadIdx.x;
  const int w = tid >> 6, lane = tid & 63;
  const int l15 = lane & 15, g = lane >> 4;
  const int r0 = blockIdx.x * 32;

  {
    float4 g4 = *(const float4*)(g0v + lane*4);
    float4 b4 = *(const float4*)(b0v + lane*4);
    #pragma unroll
    for (int rr = 0; rr < 4; ++rr) {
      int m = w*4 + rr;
      const float* xr = x + (size_t)(r0 + m) * 256;
      float4 v = *(const float4*)(xr + lane*4);
      float s = v.x + v.y + v.z + v.w;
      #pragma unroll
      for (int mk = 1; mk <= 32; mk <<= 1) s += __shfl_xor(s, mk, 64);
      float mu = s * (1.0f/256.0f);
      float dx = v.x-mu, dy = v.y-mu, dz = v.z-mu, dw = v.w-mu;
      float qq = dx*dx + dy*dy + dz*dz + dw*dw;
      #pragma unroll
      for (int mk = 1; mk <= 32; mk <<= 1) qq += __shfl_xor(qq, mk, 64);
      float rstd = rsqrtf(qq * (1.0f/256.0f) + 1e-5f);
      if (lane == 0) { mu_[m] = mu; rs_[m] = rstd; }
      float nx = dx*rstd*g4.x + b4.x;
      float ny = dy*rstd*g4.y + b4.y;
      float nz = dz*rstd*g4.z + b4.z;
      float nw = dw*rstd*g4.w + b4.w;
      int2 pv = { pk2(nx, ny), pk2(nz, nw) };
      *(int2*)&As[m][SWZ(m, lane*4)] = pv;
    }
  }
  __syncthreads();

  const int m0 = (w >> 2) * 16;
  const int e0 = (w & 3) * 64;
  f32x4 acc4[4];
  #pragma unroll
  for (int j = 0; j < 4; ++j)
    #pragma unroll
    for (int r = 0; r < 4; ++r) acc4[j][r] = 0.f;

  for (int k0 = 0; k0 < 256; k0 += 64) {
    if (k0) __syncthreads();
    {
      const int ch = tid & 7;
      const int er = tid >> 3;
      #pragma unroll
      for (int p = 0; p < 4; ++p) {
        int e = p*64 + er;
        const float* wp = Wo + (size_t)e*256 + k0 + ch*8;
        float4 u0 = *(const float4*)wp;
        float4 u1 = *(const float4*)(wp + 4);
        int4 pk = { pk2(u0.x,u0.y), pk2(u0.z,u0.w), pk2(u1.x,u1.y), pk2(u1.z,u1.w) };
        *(int4*)&Ws[e][SWZ(e, ch*8)] = pk;
      }
    }
    __syncthreads();
    __builtin_amdgcn_s_setprio(1);
    #pragma unroll
    for (int ds_ = 0; ds_ < 2; ++ds_) {
      int ma = m0 + l15;
      bf16x8 af = *(const bf16x8*)&As[ma][SWZ(ma, k0 + ds_*32 + g*8)];
      #pragma unroll
      for (int j = 0; j < 4; ++j) {
        int er = e0 + j*16 + l15;
        bf16x8 bfv = *(const bf16x8*)&Ws[er][SWZ(er, ds_*32 + g*8)];
        acc4[j] = __builtin_amdgcn_mfma_f32_16x16x32_bf16(af, bfv, acc4[j], 0, 0, 0);
      }
    }
    __builtin_amdgcn_s_setprio(0);
  }
  __syncthreads();

  #pragma unroll
  for (int j = 0; j < 4; ++j) {
    int e = e0 + j*16 + l15;
    float bov = bo[e], g0e = g0v[e], b0e = b0v[e];
    #pragma unroll
    for (int r = 0; r < 4; ++r) {
      int m = m0 + g*4 + r;
      float xv = x[(size_t)(r0 + m)*256 + e];
      float resv = (xv - mu_[m]) * rs_[m] * g0e + b0e;
      float val = acc4[j][r] + bov;
      P[m*256 + e] = resv + fmaxf(val, 0.f);
    }
  }
  __syncthreads();

  {
    float4 g4 = *(const float4*)(g1v + lane*4);
    float4 b4 = *(const float4*)(b1v + lane*4);
    #pragma unroll
    for (int rr = 0; rr < 4; ++rr) {
      int m = w*4 + rr;
      float4 v = *(const float4*)&P[m*256 + lane*4];
      float s = v.x + v.y + v.z + v.w;
      #pragma unroll
      for (int mk = 1; mk <= 32; mk <<= 1) s += __shfl_xor(s, mk, 64);
      float mu = s * (1.0f/256.0f);
      float dx = v.x-mu, dy = v.y-mu, dz = v.z-mu, dw = v.w-mu;
      float qq = dx*dx + dy*dy + dz*dz + dw*dw;
      #pragma unroll
      for (int mk = 1; mk <= 32; mk <<= 1) qq += __shfl_xor(qq, mk, 64);
      float rstd = rsqrtf(qq * (1.0f/256.0f) + 1e-5f);
      float4 o;
      o.x = dx*rstd*g4.x + b4.x; o.y = dy*rstd*g4.y + b4.y;
      o.z = dz*rstd*g4.z + b4.z; o.w = dw*rstd*g4.w + b4.w;
      *(float4*)(y + (size_t)(r0 + m)*256 + lane*4) = o;
    }
  }
}

// ---------------------------------------------------------------------------
extern "C" void kernel_launch(void* const* d_in, const int* in_sizes, int n_in,
                              void* d_out, int out_size, void* d_ws, size_t ws_size,
                              hipStream_t stream) {
  const float* Q  = (const float*)d_in[0];
  const float* K  = (const float*)d_in[1];
  const float* Wq = (const float*)d_in[2];
  const float* bq = (const float*)d_in[3];
  const float* Wk = (const float*)d_in[4];
  const float* bk = (const float*)d_in[5];
  const float* Wv = (const float*)d_in[6];
  const float* bv = (const float*)d_in[7];
  const float* Wo = (const float*)d_in[8];
  const float* bo = (const float*)d_in[9];
  const float* g0 = (const float*)d_in[10];
  const float* b0 = (const float*)d_in[11];
  const float* g1 = (const float*)d_in[12];
  const float* b1 = (const float*)d_in[13];
  float* out = (float*)d_out;

  const size_t SZ = (size_t)4 * 2048 * 256;
  if (ws_size < 2 * SZ * sizeof(unsigned short)) return;  // need 8 MB

  unsigned short* kbf = (unsigned short*)d_ws;
  unsigned short* vtb = kbf + SZ;

  const int LDS = 65536;
  (void)hipFuncSetAttribute((const void*)mab_mega,
                            hipFuncAttributeMaxDynamicSharedMemorySize, LDS);

  void* args[] = { (void*)&Q, (void*)&K, (void*)&Wq, (void*)&bq,
                   (void*)&Wk, (void*)&bk, (void*)&Wv, (void*)&bv,
                   (void*)&Wo, (void*)&bo, (void*)&g0, (void*)&b0,
                   (void*)&g1, (void*)&b1, (void*)&out, (void*)&kbf,
                   (void*)&vtb };
  hipError_t err = hipLaunchCooperativeKernel(
      (const void*)mab_mega, dim3(256), dim3(512), args, LDS, stream);

  if (err != hipSuccess) {
    // Fallback: validated round-9 three-kernel path.
    (void)hipGetLastError();  // clear sticky error
    (void)hipFuncSetAttribute((const void*)attn_mfma6,
                              hipFuncAttributeMaxDynamicSharedMemorySize, LDS);
    proj_kernel<<<dim3(4, 128, 3), dim3(256), 0, stream>>>(
        Q, K, Wq, bq, Wk, bk, Wv, bv, out, kbf, vtb);
    attn_mfma6<<<dim3(512), dim3(512), LDS, stream>>>(out, kbf, vtb, out);
    fused_out<<<dim3(256), dim3(512), 0, stream>>>(out, Wo, bo, g0, b0, g1, b1, out);
  }
}

// Round 15
// 68.009 us; speedup vs baseline: 4.6057x; 4.6057x over previous
//
#include <hip/hip_runtime.h>
#include <hip/hip_bf16.h>
#include <math.h>

// MAB: q=QWq^T+bq; k=KWk^T+bk; v=KWv^T+bv; per-head softmax(qk^T/16)v + q-residual;
// LN0; +relu(GEMM Wo); LN1.  B=4, N=2048, D=256, H=4, Dh=64.
// Round 15: validated round-9 trio, with proj upgraded to A-slab LDS reuse
// (stage 64x256 bf16 A once, loop 2 bn tiles; halves A re-reads, 768 blocks).
// attn_mfma6 + fused_out byte-identical to round 9 (best: 69.6us).
// ws (8 MB): [0,4MB) k bf16 [8192][256]; [4,8MB) v_t bf16 [16][64][2048].

typedef __attribute__((ext_vector_type(8))) short bf16x8;
typedef __attribute__((ext_vector_type(4))) float f32x4;

static __device__ __forceinline__ unsigned short f2bf(float x) {
  return __bfloat16_as_ushort(__float2bfloat16(x));
}
static __device__ __forceinline__ int pk2(float lo, float hi) {
  return (int)((unsigned)f2bf(lo) | ((unsigned)f2bf(hi) << 16));
}
static __device__ __forceinline__ float exp2_fast(float x) {
  float r; asm("v_exp_f32 %0, %1" : "=v"(r) : "v"(x)); return r;
}

#define SWZ(row, col) ((col) ^ (((row) & 7) << 3))

typedef unsigned short tile64_t[64][64];

// ---------------------------------------------------------------------------
// proj2: A-slab-reuse projection. grid (2, 128, 3), 256 threads.
// Block: bm = blockIdx.y (64 A-rows), z = blockIdx.z, bn in {x, x+2}.
// A slab (64x256) staged to LDS bf16 ONCE; W tile (64x64) per (bn,k0).
// z=0: q -> fp32 qout; z=1: k -> bf16 kbf; z=2: v -> bf16 transposed vtb.
// MFMA order per (bn,k0,kc) identical to round-9 proj -> bit-identical output.
// ---------------------------------------------------------------------------
__global__ __launch_bounds__(256, 2) void proj2_kernel(
    const float* __restrict__ Q, const float* __restrict__ K,
    const float* __restrict__ Wq, const float* __restrict__ bq,
    const float* __restrict__ Wk, const float* __restrict__ bk,
    const float* __restrict__ Wv, const float* __restrict__ bv,
    float* __restrict__ qout, unsigned short* __restrict__ kbf,
    unsigned short* __restrict__ vtb)
{
  __shared__ __align__(16) unsigned short Ab[64][256];   // 32 KB
  __shared__ __align__(16) unsigned short Wb[64][64];    // 8 KB
  const int tid = threadIdx.x;
  const int z = blockIdx.z;
  const int bm = blockIdx.y;

  const float* A    = (z == 0) ? Q  : K;
  const float* W    = (z == 0) ? Wq : ((z == 1) ? Wk : Wv);
  const float* bias = (z == 0) ? bq : ((z == 1) ? bk : bv);

  const int wid = tid >> 6, lane = tid & 63;
  const int l15 = lane & 15, g = lane >> 4;
  const int wr = wid >> 1, wc = wid & 1;
  const float* Ablk = A + (size_t)bm * 64 * 256;

  const int sr = tid >> 2, sc = (tid & 3) * 16;
  const int c0 = SWZ(sr, sc), c1 = SWZ(sr, sc + 8);

  // ---- stage full A slab (64 rows x 256 cols) as bf16, once
  #pragma unroll
  for (int kb = 0; kb < 4; ++kb) {
    const float* ap = Ablk + (size_t)sr*256 + kb*64 + sc;
    float4 a0 = *(const float4*)ap,       a1 = *(const float4*)(ap + 4);
    float4 a2 = *(const float4*)(ap + 8), a3 = *(const float4*)(ap + 12);
    int4 p0 = { pk2(a0.x,a0.y), pk2(a0.z,a0.w), pk2(a1.x,a1.y), pk2(a1.z,a1.w) };
    int4 p1 = { pk2(a2.x,a2.y), pk2(a2.z,a2.w), pk2(a3.x,a3.y), pk2(a3.z,a3.w) };
    *(int4*)&Ab[sr][kb*64 + c0] = p0;
    *(int4*)&Ab[sr][kb*64 + c1] = p1;
  }

  for (int bi = 0; bi < 2; ++bi) {
    const int bn = blockIdx.x + bi*2;
    const float* Wblk = W + (size_t)bn * 64 * 256;

    f32x4 acc[2][2];
    #pragma unroll
    for (int i = 0; i < 2; ++i)
      #pragma unroll
      for (int j = 0; j < 2; ++j)
        #pragma unroll
        for (int r = 0; r < 4; ++r) acc[i][j][r] = 0.f;

    for (int k0 = 0; k0 < 256; k0 += 64) {
      if (bi | k0) __syncthreads();     // prior Wb readers done
      {
        const float* wp = Wblk + (size_t)sr*256 + k0 + sc;
        float4 w0 = *(const float4*)wp,       w1 = *(const float4*)(wp + 4);
        float4 w2 = *(const float4*)(wp + 8), w3 = *(const float4*)(wp + 12);
        int4 p0 = { pk2(w0.x,w0.y), pk2(w0.z,w0.w), pk2(w1.x,w1.y), pk2(w1.z,w1.w) };
        int4 p1 = { pk2(w2.x,w2.y), pk2(w2.z,w2.w), pk2(w3.x,w3.y), pk2(w3.z,w3.w) };
        *(int4*)&Wb[sr][c0] = p0;
        *(int4*)&Wb[sr][c1] = p1;
      }
      __syncthreads();                  // Wb (and first-time Ab) visible

      __builtin_amdgcn_s_setprio(1);
      #pragma unroll
      for (int kc = 0; kc < 64; kc += 32) {
        bf16x8 af[2], bf_[2];
        #pragma unroll
        for (int i = 0; i < 2; ++i) {
          int ra = wr*32 + i*16 + l15;
          int rb = wc*32 + i*16 + l15;
          // A-operand: rows from Ab for q/k (z<2), from Wb for v (z==2)
          if (z == 2) {
            af[i]  = *(const bf16x8*)&Wb[ra][SWZ(ra, kc + g*8)];
            bf_[i] = *(const bf16x8*)&Ab[rb][k0 + SWZ(rb, kc + g*8)];
          } else {
            af[i]  = *(const bf16x8*)&Ab[ra][k0 + SWZ(ra, kc + g*8)];
            bf_[i] = *(const bf16x8*)&Wb[rb][SWZ(rb, kc + g*8)];
          }
        }
        #pragma unroll
        for (int i = 0; i < 2; ++i)
          #pragma unroll
          for (int j = 0; j < 2; ++j)
            acc[i][j] = __builtin_amdgcn_mfma_f32_16x16x32_bf16(af[i], bf_[j], acc[i][j], 0, 0, 0);
      }
      __builtin_amdgcn_s_setprio(0);
    }

    if (z == 2) {
      // v: C row axis = d (from W), col axis = n (from A); write vtb[bh][d][n]
      const int bvb = bm >> 5;
      const int n0 = (bm & 31) * 64 + wc*32;
      #pragma unroll
      for (int di = 0; di < 2; ++di)
        #pragma unroll
        for (int r = 0; r < 4; ++r) {
          int d = wr*32 + di*16 + g*4 + r;
          float bvs = bias[bn*64 + d];
          #pragma unroll
          for (int ni = 0; ni < 2; ++ni) {
            float c = acc[di][ni][r] + bvs;
            vtb[((size_t)(bvb*4 + bn)*64 + d)*2048 + n0 + ni*16 + l15] = f2bf(c);
          }
        }
    } else {
      const int gm = bm*64 + wr*32, ge = bn*64 + wc*32;
      float bv0 = bias[ge + l15], bv1 = bias[ge + 16 + l15];
      #pragma unroll
      for (int mi = 0; mi < 2; ++mi)
        #pragma unroll
        for (int r = 0; r < 4; ++r) {
          int row = gm + mi*16 + g*4 + r;
          #pragma unroll
          for (int ei = 0; ei < 2; ++ei) {
            float c = acc[mi][ei][r] + (ei ? bv1 : bv0);
            if (z == 0) qout[(size_t)row*256 + ge + ei*16 + l15] = c;
            else        kbf [(size_t)row*256 + ge + ei*16 + l15] = f2bf(c);
          }
        }
    }
  }
}

// ---------------------------------------------------------------------------
// attn_mfma6 (round-9 validated, byte-identical): KV-split x2, dbuf K/V,
// no-max exp2 softmax, in-register P via cvt_pk + permlane.
// ---------------------------------------------------------------------------
__global__ __launch_bounds__(512, 4) void attn_mfma6(
    const float* __restrict__ q,
    const unsigned short* __restrict__ kb,
    const unsigned short* __restrict__ vt,
    float* __restrict__ o)
{
  extern __shared__ __align__(16) char smem_dyn[];
  tile64_t* Ks = (tile64_t*)smem_dyn;
  tile64_t* Vt = (tile64_t*)(smem_dyn + 32768);

  const int tid = threadIdx.x;
  const int wid = tid >> 6;
  const int grp = wid >> 2;
  const int w4  = wid & 3;
  const int lane = tid & 63;
  const int l15 = lane & 15;
  const int g = lane >> 4;
  const int lin = blockIdx.x;
  const int xcd = lin & 7, idx = lin >> 3;
  const int bh = xcd * 2 + (idx >> 5);
  const int qb = idx & 31;
  const int b = bh >> 2, h = bh & 3;

  const float qscale = 0.0625f * 1.44269504089f;
  bf16x8 qf[2];
  {
    const float* qp = q + ((size_t)(b*2048 + qb*64 + w4*16 + l15))*256 + h*64;
    #pragma unroll
    for (int ds_ = 0; ds_ < 2; ++ds_) {
      union { bf16x8 v; unsigned short s[8]; } tmp;
      #pragma unroll
      for (int j = 0; j < 8; ++j) tmp.s[j] = f2bf(qp[ds_*32 + g*8 + j] * qscale);
      qf[ds_] = tmp.v;
    }
  }

  const int gt = tid & 255;
  const int sr = gt >> 2, sc = (gt & 3) * 16;
  const int c0 = SWZ(sr, sc), c1 = SWZ(sr, sc + 8);
  const unsigned short* kgp = kb + ((size_t)(b*2048 + grp*1024 + sr))*256 + h*64 + sc;
  const unsigned short* vgp = vt + ((size_t)bh*64 + sr)*2048 + grp*1024 + sc;

  f32x4 oa[4];
  #pragma unroll
  for (int mt = 0; mt < 4; ++mt)
    #pragma unroll
    for (int r = 0; r < 4; ++r) oa[mt][r] = 0.f;
  float l_ = 0.f;

  {
    int4 k0_ = *(const int4*)kgp, k1_ = *(const int4*)(kgp + 8);
    int4 v0_ = *(const int4*)vgp, v1_ = *(const int4*)(vgp + 8);
    *(int4*)&Ks[grp*2+0][sr][c0] = k0_;  *(int4*)&Ks[grp*2+0][sr][c1] = k1_;
    *(int4*)&Vt[grp*2+0][sr][c0] = v0_;  *(int4*)&Vt[grp*2+0][sr][c1] = v1_;
  }
  int4 kA0 = *(const int4*)(kgp + (size_t)64*256);
  int4 kA1 = *(const int4*)(kgp + (size_t)64*256 + 8);
  int4 vA0 = *(const int4*)(vgp + 64);
  int4 vA1 = *(const int4*)(vgp + 64 + 8);
  __syncthreads();

  for (int kt = 0; kt < 16; ++kt) {
    const int cur = kt & 1;
    const tile64_t& Kc = Ks[grp*2 + cur];
    const tile64_t& Vc = Vt[grp*2 + cur];

    f32x4 sa[4];
    #pragma unroll
    for (int mt = 0; mt < 4; ++mt)
      #pragma unroll
      for (int r = 0; r < 4; ++r) sa[mt][r] = 0.f;
    __builtin_amdgcn_s_setprio(1);
    #pragma unroll
    for (int ds_ = 0; ds_ < 2; ++ds_) {
      #pragma unroll
      for (int mt = 0; mt < 4; ++mt) {
        bf16x8 af = *(const bf16x8*)&Kc[mt*16 + l15][SWZ(l15, ds_*32 + g*8)];
        sa[mt] = __builtin_amdgcn_mfma_f32_16x16x32_bf16(af, qf[ds_], sa[mt], 0, 0, 0);
      }
    }
    __builtin_amdgcn_s_setprio(0);

    float ps = 0.f;
    unsigned pk01[4], pk23[4];
    #pragma unroll
    for (int mt = 0; mt < 4; ++mt) {
      float p0 = exp2_fast(sa[mt][0]);
      float p1 = exp2_fast(sa[mt][1]);
      float p2 = exp2_fast(sa[mt][2]);
      float p3 = exp2_fast(sa[mt][3]);
      ps += (p0 + p1) + (p2 + p3);
      pk01[mt] = (unsigned)pk2(p0, p1);
      pk23[mt] = (unsigned)pk2(p2, p3);
    }
    ps += __shfl_xor(ps, 16, 64);
    ps += __shfl_xor(ps, 32, 64);
    l_ += ps;

    __builtin_amdgcn_s_setprio(1);
    #pragma unroll
    for (int ks_ = 0; ks_ < 2; ++ks_) {
      unsigned a0 = pk01[2*ks_], b0 = pk01[2*ks_ + 1];
      unsigned a1 = pk23[2*ks_], b1 = pk23[2*ks_ + 1];
      asm volatile("v_permlane32_swap_b32 %0, %1" : "+v"(a0), "+v"(b0));
      asm volatile("v_permlane16_swap_b32 %0, %1" : "+v"(a0), "+v"(b0));
      asm volatile("v_permlane32_swap_b32 %0, %1" : "+v"(a1), "+v"(b1));
      asm volatile("v_permlane16_swap_b32 %0, %1" : "+v"(a1), "+v"(b1));
      int4 pw = { (int)a0, (int)a1, (int)b0, (int)b1 };
      bf16x8 pf = __builtin_bit_cast(bf16x8, pw);
      #pragma unroll
      for (int mt = 0; mt < 4; ++mt) {
        bf16x8 vf = *(const bf16x8*)&Vc[mt*16 + l15][SWZ(l15, ks_*32 + g*8)];
        oa[mt] = __builtin_amdgcn_mfma_f32_16x16x32_bf16(vf, pf, oa[mt], 0, 0, 0);
      }
    }
    __builtin_amdgcn_s_setprio(0);

    if (kt < 15) {
      *(int4*)&Ks[grp*2+(cur^1)][sr][c0] = kA0;
      *(int4*)&Ks[grp*2+(cur^1)][sr][c1] = kA1;
      *(int4*)&Vt[grp*2+(cur^1)][sr][c0] = vA0;
      *(int4*)&Vt[grp*2+(cur^1)][sr][c1] = vA1;
      if (kt < 14) {
        const unsigned short* kn = kgp + (size_t)(kt + 2) * 64 * 256;
        const unsigned short* vn = vgp + (kt + 2) * 64;
        kA0 = *(const int4*)kn;  kA1 = *(const int4*)(kn + 8);
        vA0 = *(const int4*)vn;  vA1 = *(const int4*)(vn + 8);
      }
    }
    __syncthreads();
  }

  float* cob = (float*)smem_dyn;
  float* cml = (float*)(smem_dyn + 32768);
  const int ci = w4*64 + lane;
  if (grp == 1) {
    #pragma unroll
    for (int mt = 0; mt < 4; ++mt)
      #pragma unroll
      for (int r = 0; r < 4; ++r) cob[(mt*4 + r)*256 + ci] = oa[mt][r];
    cml[ci] = l_;
  }
  __syncthreads();
  if (grp == 0) {
    float linv = 1.0f / (l_ + cml[ci]);
    float* op = o + ((size_t)(b*2048 + qb*64 + w4*16 + l15))*256 + h*64;
    #pragma unroll
    for (int mt = 0; mt < 4; ++mt) {
      int dbase = mt*16 + g*4;
      float4 qv = *(const float4*)(op + dbase);
      float4 st;
      st.x = qv.x + (oa[mt][0] + cob[(mt*4+0)*256 + ci]) * linv;
      st.y = qv.y + (oa[mt][1] + cob[(mt*4+1)*256 + ci]) * linv;
      st.z = qv.z + (oa[mt][2] + cob[(mt*4+2)*256 + ci]) * linv;
      st.w = qv.w + (oa[mt][3] + cob[(mt*4+3)*256 + ci]) * linv;
      *(float4*)(op + dbase) = st;
    }
  }
}

// ---------------------------------------------------------------------------
// fused_out (round-9 validated, byte-identical): LN0 + res+relu(GEMM Wo) + LN1.
// ---------------------------------------------------------------------------
__global__ __launch_bounds__(512) void fused_out(
    const float* __restrict__ x, const float* __restrict__ Wo,
    const float* __restrict__ bo,
    const float* __restrict__ g0v, const float* __restrict__ b0v,
    const float* __restrict__ g1v, const float* __restrict__ b1v,
    float* __restrict__ y)
{
  __shared__ __align__(16) unsigned short As[32][256];
  __shared__ __align__(16) unsigned short Ws[256][64];
  __shared__ float mu_[32], rs_[32];
  float* P = (float*)&Ws[0][0];

  const int tid = threadIdx.x;
  const int w = tid >> 6, lane = tid & 63;
  const int l15 = lane & 15, g = lane >> 4;
  const int r0 = blockIdx.x * 32;

  {
    float4 g4 = *(const float4*)(g0v + lane*4);
    float4 b4 = *(const float4*)(b0v + lane*4);
    #pragma unroll
    for (int rr = 0; rr < 4; ++rr) {
      int m = w*4 + rr;
      const float* xr = x + (size_t)(r0 + m) * 256;
      float4 v = *(const float4*)(xr + lane*4);
      float s = v.x + v.y + v.z + v.w;
      #pragma unroll
      for (int mk = 1; mk <= 32; mk <<= 1) s += __shfl_xor(s, mk, 64);
      float mu = s * (1.0f/256.0f);
      float dx = v.x-mu, dy = v.y-mu, dz = v.z-mu, dw = v.w-mu;
      float qq = dx*dx + dy*dy + dz*dz + dw*dw;
      #pragma unroll
      for (int mk = 1; mk <= 32; mk <<= 1) qq += __shfl_xor(qq, mk, 64);
      float rstd = rsqrtf(qq * (1.0f/256.0f) + 1e-5f);
      if (lane == 0) { mu_[m] = mu; rs_[m] = rstd; }
      float nx = dx*rstd*g4.x + b4.x;
      float ny = dy*rstd*g4.y + b4.y;
      float nz = dz*rstd*g4.z + b4.z;
      float nw = dw*rstd*g4.w + b4.w;
      int2 pv = { pk2(nx, ny), pk2(nz, nw) };
      *(int2*)&As[m][SWZ(m, lane*4)] = pv;
    }
  }
  __syncthreads();

  const int m0 = (w >> 2) * 16;
  const int e0 = (w & 3) * 64;
  f32x4 acc4[4];
  #pragma unroll
  for (int j = 0; j < 4; ++j)
    #pragma unroll
    for (int r = 0; r < 4; ++r) acc4[j][r] = 0.f;

  for (int k0 = 0; k0 < 256; k0 += 64) {
    if (k0) __syncthreads();
    {
      const int ch = tid & 7;
      const int er = tid >> 3;
      #pragma unroll
      for (int p = 0; p < 4; ++p) {
        int e = p*64 + er;
        const float* wp = Wo + (size_t)e*256 + k0 + ch*8;
        float4 u0 = *(const float4*)wp;
        float4 u1 = *(const float4*)(wp + 4);
        int4 pk = { pk2(u0.x,u0.y), pk2(u0.z,u0.w), pk2(u1.x,u1.y), pk2(u1.z,u1.w) };
        *(int4*)&Ws[e][SWZ(e, ch*8)] = pk;
      }
    }
    __syncthreads();
    __builtin_amdgcn_s_setprio(1);
    #pragma unroll
    for (int ds_ = 0; ds_ < 2; ++ds_) {
      int ma = m0 + l15;
      bf16x8 af = *(const bf16x8*)&As[ma][SWZ(ma, k0 + ds_*32 + g*8)];
      #pragma unroll
      for (int j = 0; j < 4; ++j) {
        int er = e0 + j*16 + l15;
        bf16x8 bfv = *(const bf16x8*)&Ws[er][SWZ(er, ds_*32 + g*8)];
        acc4[j] = __builtin_amdgcn_mfma_f32_16x16x32_bf16(af, bfv, acc4[j], 0, 0, 0);
      }
    }
    __builtin_amdgcn_s_setprio(0);
  }
  __syncthreads();

  #pragma unroll
  for (int j = 0; j < 4; ++j) {
    int e = e0 + j*16 + l15;
    float bov = bo[e], g0e = g0v[e], b0e = b0v[e];
    #pragma unroll
    for (int r = 0; r < 4; ++r) {
      int m = m0 + g*4 + r;
      float xv = x[(size_t)(r0 + m)*256 + e];
      float resv = (xv - mu_[m]) * rs_[m] * g0e + b0e;
      float val = acc4[j][r] + bov;
      P[m*256 + e] = resv + fmaxf(val, 0.f);
    }
  }
  __syncthreads();

  {
    float4 g4 = *(const float4*)(g1v + lane*4);
    float4 b4 = *(const float4*)(b1v + lane*4);
    #pragma unroll
    for (int rr = 0; rr < 4; ++rr) {
      int m = w*4 + rr;
      float4 v = *(const float4*)&P[m*256 + lane*4];
      float s = v.x + v.y + v.z + v.w;
      #pragma unroll
      for (int mk = 1; mk <= 32; mk <<= 1) s += __shfl_xor(s, mk, 64);
      float mu = s * (1.0f/256.0f);
      float dx = v.x-mu, dy = v.y-mu, dz = v.z-mu, dw = v.w-mu;
      float qq = dx*dx + dy*dy + dz*dz + dw*dw;
      #pragma unroll
      for (int mk = 1; mk <= 32; mk <<= 1) qq += __shfl_xor(qq, mk, 64);
      float rstd = rsqrtf(qq * (1.0f/256.0f) + 1e-5f);
      float4 o;
      o.x = dx*rstd*g4.x + b4.x; o.y = dy*rstd*g4.y + b4.y;
      o.z = dz*rstd*g4.z + b4.z; o.w = dw*rstd*g4.w + b4.w;
      *(float4*)(y + (size_t)(r0 + m)*256 + lane*4) = o;
    }
  }
}

// ---------------------------------------------------------------------------
extern "C" void kernel_launch(void* const* d_in, const int* in_sizes, int n_in,
                              void* d_out, int out_size, void* d_ws, size_t ws_size,
                              hipStream_t stream) {
  const float* Q  = (const float*)d_in[0];
  const float* K  = (const float*)d_in[1];
  const float* Wq = (const float*)d_in[2];
  const float* bq = (const float*)d_in[3];
  const float* Wk = (const float*)d_in[4];
  const float* bk = (const float*)d_in[5];
  const float* Wv = (const float*)d_in[6];
  const float* bv = (const float*)d_in[7];
  const float* Wo = (const float*)d_in[8];
  const float* bo = (const float*)d_in[9];
  const float* g0 = (const float*)d_in[10];
  const float* b0 = (const float*)d_in[11];
  const float* g1 = (const float*)d_in[12];
  const float* b1 = (const float*)d_in[13];
  float* out = (float*)d_out;

  const size_t SZ = (size_t)4 * 2048 * 256;
  if (ws_size < 2 * SZ * sizeof(unsigned short)) return;  // need 8 MB

  unsigned short* kbf = (unsigned short*)d_ws;
  unsigned short* vtb = kbf + SZ;

  const int ATTN_LDS = 65536;
  hipFuncSetAttribute((const void*)attn_mfma6,
                      hipFuncAttributeMaxDynamicSharedMemorySize, ATTN_LDS);

  proj2_kernel<<<dim3(2, 128, 3), dim3(256), 0, stream>>>(
      Q, K, Wq, bq, Wk, bk, Wv, bv, out, kbf, vtb);
  attn_mfma6<<<dim3(512), dim3(512), ATTN_LDS, stream>>>(out, kbf, vtb, out);
  fused_out<<<dim3(256), dim3(512), 0, stream>>>(out, Wo, bo, g0, b0, g1, b1, out);
}

// Round 16
// 67.022 us; speedup vs baseline: 4.6736x; 1.0147x over previous
//
#include <hip/hip_runtime.h>
#include <hip/hip_bf16.h>
#include <math.h>

// MAB: q=QWq^T+bq; k=KWk^T+bk; v=KWv^T+bv; per-head softmax(qk^T/16)v + q-residual;
// LN0; +relu(GEMM Wo); LN1.  B=4, N=2048, D=256, H=4, Dh=64.
// Round 16: attn v10 = v6 + cross-tile software pipeline: QK[t+1] issued before
// PV[t], so softmax[t+1] (VALU) overlaps PV[t] (MFMA) across the barrier, and
// stage-writes hide under softmax[t]. Same per-tile math as v6 (bit-identical).
// proj2 + fused_out byte-identical to round 15 (validated).
// ws (8 MB): [0,4MB) k bf16 [8192][256]; [4,8MB) v_t bf16 [16][64][2048].

typedef __attribute__((ext_vector_type(8))) short bf16x8;
typedef __attribute__((ext_vector_type(4))) float f32x4;

static __device__ __forceinline__ unsigned short f2bf(float x) {
  return __bfloat16_as_ushort(__float2bfloat16(x));
}
static __device__ __forceinline__ int pk2(float lo, float hi) {
  return (int)((unsigned)f2bf(lo) | ((unsigned)f2bf(hi) << 16));
}
static __device__ __forceinline__ float exp2_fast(float x) {
  float r; asm("v_exp_f32 %0, %1" : "=v"(r) : "v"(x)); return r;
}

#define SWZ(row, col) ((col) ^ (((row) & 7) << 3))

typedef unsigned short tile64_t[64][64];

// ---------------------------------------------------------------------------
// proj2 (round-15 validated, byte-identical): A-slab-reuse projections.
// ---------------------------------------------------------------------------
__global__ __launch_bounds__(256, 2) void proj2_kernel(
    const float* __restrict__ Q, const float* __restrict__ K,
    const float* __restrict__ Wq, const float* __restrict__ bq,
    const float* __restrict__ Wk, const float* __restrict__ bk,
    const float* __restrict__ Wv, const float* __restrict__ bv,
    float* __restrict__ qout, unsigned short* __restrict__ kbf,
    unsigned short* __restrict__ vtb)
{
  __shared__ __align__(16) unsigned short Ab[64][256];
  __shared__ __align__(16) unsigned short Wb[64][64];
  const int tid = threadIdx.x;
  const int z = blockIdx.z;
  const int bm = blockIdx.y;

  const float* A    = (z == 0) ? Q  : K;
  const float* W    = (z == 0) ? Wq : ((z == 1) ? Wk : Wv);
  const float* bias = (z == 0) ? bq : ((z == 1) ? bk : bv);

  const int wid = tid >> 6, lane = tid & 63;
  const int l15 = lane & 15, g = lane >> 4;
  const int wr = wid >> 1, wc = wid & 1;
  const float* Ablk = A + (size_t)bm * 64 * 256;

  const int sr = tid >> 2, sc = (tid & 3) * 16;
  const int c0 = SWZ(sr, sc), c1 = SWZ(sr, sc + 8);

  #pragma unroll
  for (int kb = 0; kb < 4; ++kb) {
    const float* ap = Ablk + (size_t)sr*256 + kb*64 + sc;
    float4 a0 = *(const float4*)ap,       a1 = *(const float4*)(ap + 4);
    float4 a2 = *(const float4*)(ap + 8), a3 = *(const float4*)(ap + 12);
    int4 p0 = { pk2(a0.x,a0.y), pk2(a0.z,a0.w), pk2(a1.x,a1.y), pk2(a1.z,a1.w) };
    int4 p1 = { pk2(a2.x,a2.y), pk2(a2.z,a2.w), pk2(a3.x,a3.y), pk2(a3.z,a3.w) };
    *(int4*)&Ab[sr][kb*64 + c0] = p0;
    *(int4*)&Ab[sr][kb*64 + c1] = p1;
  }

  for (int bi = 0; bi < 2; ++bi) {
    const int bn = blockIdx.x + bi*2;
    const float* Wblk = W + (size_t)bn * 64 * 256;

    f32x4 acc[2][2];
    #pragma unroll
    for (int i = 0; i < 2; ++i)
      #pragma unroll
      for (int j = 0; j < 2; ++j)
        #pragma unroll
        for (int r = 0; r < 4; ++r) acc[i][j][r] = 0.f;

    for (int k0 = 0; k0 < 256; k0 += 64) {
      if (bi | k0) __syncthreads();
      {
        const float* wp = Wblk + (size_t)sr*256 + k0 + sc;
        float4 w0 = *(const float4*)wp,       w1 = *(const float4*)(wp + 4);
        float4 w2 = *(const float4*)(wp + 8), w3 = *(const float4*)(wp + 12);
        int4 p0 = { pk2(w0.x,w0.y), pk2(w0.z,w0.w), pk2(w1.x,w1.y), pk2(w1.z,w1.w) };
        int4 p1 = { pk2(w2.x,w2.y), pk2(w2.z,w2.w), pk2(w3.x,w3.y), pk2(w3.z,w3.w) };
        *(int4*)&Wb[sr][c0] = p0;
        *(int4*)&Wb[sr][c1] = p1;
      }
      __syncthreads();

      __builtin_amdgcn_s_setprio(1);
      #pragma unroll
      for (int kc = 0; kc < 64; kc += 32) {
        bf16x8 af[2], bf_[2];
        #pragma unroll
        for (int i = 0; i < 2; ++i) {
          int ra = wr*32 + i*16 + l15;
          int rb = wc*32 + i*16 + l15;
          if (z == 2) {
            af[i]  = *(const bf16x8*)&Wb[ra][SWZ(ra, kc + g*8)];
            bf_[i] = *(const bf16x8*)&Ab[rb][k0 + SWZ(rb, kc + g*8)];
          } else {
            af[i]  = *(const bf16x8*)&Ab[ra][k0 + SWZ(ra, kc + g*8)];
            bf_[i] = *(const bf16x8*)&Wb[rb][SWZ(rb, kc + g*8)];
          }
        }
        #pragma unroll
        for (int i = 0; i < 2; ++i)
          #pragma unroll
          for (int j = 0; j < 2; ++j)
            acc[i][j] = __builtin_amdgcn_mfma_f32_16x16x32_bf16(af[i], bf_[j], acc[i][j], 0, 0, 0);
      }
      __builtin_amdgcn_s_setprio(0);
    }

    if (z == 2) {
      const int bvb = bm >> 5;
      const int n0 = (bm & 31) * 64 + wc*32;
      #pragma unroll
      for (int di = 0; di < 2; ++di)
        #pragma unroll
        for (int r = 0; r < 4; ++r) {
          int d = wr*32 + di*16 + g*4 + r;
          float bvs = bias[bn*64 + d];
          #pragma unroll
          for (int ni = 0; ni < 2; ++ni) {
            float c = acc[di][ni][r] + bvs;
            vtb[((size_t)(bvb*4 + bn)*64 + d)*2048 + n0 + ni*16 + l15] = f2bf(c);
          }
        }
    } else {
      const int gm = bm*64 + wr*32, ge = bn*64 + wc*32;
      float bv0 = bias[ge + l15], bv1 = bias[ge + 16 + l15];
      #pragma unroll
      for (int mi = 0; mi < 2; ++mi)
        #pragma unroll
        for (int r = 0; r < 4; ++r) {
          int row = gm + mi*16 + g*4 + r;
          #pragma unroll
          for (int ei = 0; ei < 2; ++ei) {
            float c = acc[mi][ei][r] + (ei ? bv1 : bv0);
            if (z == 0) qout[(size_t)row*256 + ge + ei*16 + l15] = c;
            else        kbf [(size_t)row*256 + ge + ei*16 + l15] = f2bf(c);
          }
        }
    }
  }
}

// ---------------------------------------------------------------------------
// attn v10: v6 + cross-tile pipeline. 512 thr = 8 waves, KV-split x2, dbuf,
// no-max softmax, in-register P via cvt_pk+permlane (all validated pieces).
// Per 2-tile iteration: {bar0; stage; softmax[A]; bar1; QK[B]; PV[A]} x2.
// softmax[t+1] overlaps PV[t]'s in-flight MFMAs (separate pipes).
// ---------------------------------------------------------------------------
#define ATT_SOFTMAX(SA, PK01, PK23, LACC)                                    \
  do {                                                                       \
    float ps_ = 0.f;                                                         \
    _Pragma("unroll")                                                        \
    for (int mt = 0; mt < 4; ++mt) {                                         \
      float p0 = exp2_fast(SA[mt][0]);                                       \
      float p1 = exp2_fast(SA[mt][1]);                                       \
      float p2 = exp2_fast(SA[mt][2]);                                       \
      float p3 = exp2_fast(SA[mt][3]);                                       \
      ps_ += (p0 + p1) + (p2 + p3);                                          \
      PK01[mt] = (unsigned)pk2(p0, p1);                                      \
      PK23[mt] = (unsigned)pk2(p2, p3);                                      \
    }                                                                        \
    ps_ += __shfl_xor(ps_, 16, 64);                                          \
    ps_ += __shfl_xor(ps_, 32, 64);                                          \
    LACC += ps_;                                                             \
  } while (0)

#define ATT_QK(SA, KBUF)                                                     \
  do {                                                                       \
    _Pragma("unroll")                                                        \
    for (int mt = 0; mt < 4; ++mt)                                           \
      _Pragma("unroll")                                                      \
      for (int r = 0; r < 4; ++r) SA[mt][r] = 0.f;                           \
    __builtin_amdgcn_s_setprio(1);                                           \
    _Pragma("unroll")                                                        \
    for (int ds_ = 0; ds_ < 2; ++ds_) {                                      \
      _Pragma("unroll")                                                      \
      for (int mt = 0; mt < 4; ++mt) {                                       \
        bf16x8 af = *(const bf16x8*)&KBUF[mt*16 + l15][SWZ(l15, ds_*32 + g*8)]; \
        SA[mt] = __builtin_amdgcn_mfma_f32_16x16x32_bf16(af, qf[ds_], SA[mt], 0, 0, 0); \
      }                                                                      \
    }                                                                        \
    __builtin_amdgcn_s_setprio(0);                                           \
  } while (0)

#define ATT_PV(PK01, PK23, VBUF)                                             \
  do {                                                                       \
    __builtin_amdgcn_s_setprio(1);                                           \
    _Pragma("unroll")                                                        \
    for (int ks_ = 0; ks_ < 2; ++ks_) {                                      \
      unsigned a0 = PK01[2*ks_], b0 = PK01[2*ks_ + 1];                       \
      unsigned a1 = PK23[2*ks_], b1 = PK23[2*ks_ + 1];                       \
      asm volatile("v_permlane32_swap_b32 %0, %1" : "+v"(a0), "+v"(b0));     \
      asm volatile("v_permlane16_swap_b32 %0, %1" : "+v"(a0), "+v"(b0));     \
      asm volatile("v_permlane32_swap_b32 %0, %1" : "+v"(a1), "+v"(b1));     \
      asm volatile("v_permlane16_swap_b32 %0, %1" : "+v"(a1), "+v"(b1));     \
      int4 pw = { (int)a0, (int)a1, (int)b0, (int)b1 };                      \
      bf16x8 pf = __builtin_bit_cast(bf16x8, pw);                            \
      _Pragma("unroll")                                                      \
      for (int mt = 0; mt < 4; ++mt) {                                       \
        bf16x8 vf = *(const bf16x8*)&VBUF[mt*16 + l15][SWZ(l15, ks_*32 + g*8)]; \
        oa[mt] = __builtin_amdgcn_mfma_f32_16x16x32_bf16(vf, pf, oa[mt], 0, 0, 0); \
      }                                                                      \
    }                                                                        \
    __builtin_amdgcn_s_setprio(0);                                           \
  } while (0)

__global__ __launch_bounds__(512, 4) void attn_mfma10(
    const float* __restrict__ q,
    const unsigned short* __restrict__ kb,
    const unsigned short* __restrict__ vt,
    float* __restrict__ o)
{
  extern __shared__ __align__(16) char smem_dyn[];
  tile64_t* Ks = (tile64_t*)smem_dyn;             // [grp*2+buf], 32 KB
  tile64_t* Vt = (tile64_t*)(smem_dyn + 32768);   // [grp*2+buf], 32 KB

  const int tid = threadIdx.x;
  const int wid = tid >> 6;
  const int grp = wid >> 2;
  const int w4  = wid & 3;
  const int lane = tid & 63;
  const int l15 = lane & 15;
  const int g = lane >> 4;
  const int lin = blockIdx.x;
  const int xcd = lin & 7, idx = lin >> 3;
  const int bh = xcd * 2 + (idx >> 5);
  const int qb = idx & 31;
  const int b = bh >> 2, h = bh & 3;

  const float qscale = 0.0625f * 1.44269504089f;
  bf16x8 qf[2];
  {
    const float* qp = q + ((size_t)(b*2048 + qb*64 + w4*16 + l15))*256 + h*64;
    #pragma unroll
    for (int ds_ = 0; ds_ < 2; ++ds_) {
      union { bf16x8 v; unsigned short s[8]; } tmp;
      #pragma unroll
      for (int j = 0; j < 8; ++j) tmp.s[j] = f2bf(qp[ds_*32 + g*8 + j] * qscale);
      qf[ds_] = tmp.v;
    }
  }

  const int gt = tid & 255;
  const int sr = gt >> 2, sc = (gt & 3) * 16;
  const int c0 = SWZ(sr, sc), c1 = SWZ(sr, sc + 8);
  const unsigned short* kgp = kb + ((size_t)(b*2048 + grp*1024 + sr))*256 + h*64 + sc;
  const unsigned short* vgp = vt + ((size_t)bh*64 + sr)*2048 + grp*1024 + sc;

  const tile64_t& K0 = Ks[grp*2 + 0];
  const tile64_t& K1 = Ks[grp*2 + 1];
  const tile64_t& V0 = Vt[grp*2 + 0];
  const tile64_t& V1 = Vt[grp*2 + 1];

  f32x4 oa[4];
  #pragma unroll
  for (int mt = 0; mt < 4; ++mt)
    #pragma unroll
    for (int r = 0; r < 4; ++r) oa[mt][r] = 0.f;
  float l_ = 0.f;

  // prologue: stage tile0 -> buf0; load regs for tile1; QK[0]
  {
    int4 k0_ = *(const int4*)kgp, k1_ = *(const int4*)(kgp + 8);
    int4 v0_ = *(const int4*)vgp, v1_ = *(const int4*)(vgp + 8);
    *(int4*)&Ks[grp*2+0][sr][c0] = k0_;  *(int4*)&Ks[grp*2+0][sr][c1] = k1_;
    *(int4*)&Vt[grp*2+0][sr][c0] = v0_;  *(int4*)&Vt[grp*2+0][sr][c1] = v1_;
  }
  int4 kA0 = *(const int4*)(kgp + (size_t)64*256);
  int4 kA1 = *(const int4*)(kgp + (size_t)64*256 + 8);
  int4 vA0 = *(const int4*)(vgp + 64);
  int4 vA1 = *(const int4*)(vgp + 64 + 8);
  __syncthreads();

  f32x4 saA[4], saB[4];
  unsigned pkA01[4], pkA23[4], pkB01[4], pkB23[4];
  ATT_QK(saA, K0);                           // tile 0

  for (int tt = 0; tt < 8; ++tt) {
    const int tA = 2*tt;                     // even tile (buf0)
    // ---------------- phase A: finish tile tA, start tile tA+1 ------------
    __syncthreads();                         // buf1 readers (PV[tA-1]) done
    {                                        // stage tile tA+1 -> buf1
      *(int4*)&Ks[grp*2+1][sr][c0] = kA0;  *(int4*)&Ks[grp*2+1][sr][c1] = kA1;
      *(int4*)&Vt[grp*2+1][sr][c0] = vA0;  *(int4*)&Vt[grp*2+1][sr][c1] = vA1;
    }
    if (tt < 7) {                            // load regs for tile tA+2
      const unsigned short* kn = kgp + (size_t)(tA + 2) * 64 * 256;
      const unsigned short* vn = vgp + (tA + 2) * 64;
      kA0 = *(const int4*)kn;  kA1 = *(const int4*)(kn + 8);
      vA0 = *(const int4*)vn;  vA1 = *(const int4*)(vn + 8);
    }
    ATT_SOFTMAX(saA, pkA01, pkA23, l_);      // softmax[tA] (hides stage writes)
    __syncthreads();                         // buf1 (tile tA+1) visible
    ATT_QK(saB, K1);                         // QK[tA+1]
    ATT_PV(pkA01, pkA23, V0);                // PV[tA] (overlaps next softmax)

    // ---------------- phase B: finish tile tA+1, start tile tA+2 ----------
    __syncthreads();                         // buf0 readers (PV[tA]) done
    if (tt < 7) {                            // stage tile tA+2 -> buf0
      *(int4*)&Ks[grp*2+0][sr][c0] = kA0;  *(int4*)&Ks[grp*2+0][sr][c1] = kA1;
      *(int4*)&Vt[grp*2+0][sr][c0] = vA0;  *(int4*)&Vt[grp*2+0][sr][c1] = vA1;
      if (tt < 7) {                          // load regs for tile tA+3
        const unsigned short* kn = kgp + (size_t)(tA + 3) * 64 * 256;
        const unsigned short* vn = vgp + (tA + 3) * 64;
        kA0 = *(const int4*)kn;  kA1 = *(const int4*)(kn + 8);
        vA0 = *(const int4*)vn;  vA1 = *(const int4*)(vn + 8);
      }
    }
    ATT_SOFTMAX(saB, pkB01, pkB23, l_);      // softmax[tA+1]
    __syncthreads();                         // buf0 (tile tA+2) visible
    if (tt < 7) ATT_QK(saA, K0);             // QK[tA+2]
    ATT_PV(pkB01, pkB23, V1);                // PV[tA+1]
  }

  // ---- merge halves (plain sums); LDS tiles dead after barrier
  __syncthreads();
  float* cob = (float*)smem_dyn;
  float* cml = (float*)(smem_dyn + 32768);
  const int ci = w4*64 + lane;
  if (grp == 1) {
    #pragma unroll
    for (int mt = 0; mt < 4; ++mt)
      #pragma unroll
      for (int r = 0; r < 4; ++r) cob[(mt*4 + r)*256 + ci] = oa[mt][r];
    cml[ci] = l_;
  }
  __syncthreads();
  if (grp == 0) {
    float linv = 1.0f / (l_ + cml[ci]);
    float* op = o + ((size_t)(b*2048 + qb*64 + w4*16 + l15))*256 + h*64;
    #pragma unroll
    for (int mt = 0; mt < 4; ++mt) {
      int dbase = mt*16 + g*4;
      float4 qv = *(const float4*)(op + dbase);
      float4 st;
      st.x = qv.x + (oa[mt][0] + cob[(mt*4+0)*256 + ci]) * linv;
      st.y = qv.y + (oa[mt][1] + cob[(mt*4+1)*256 + ci]) * linv;
      st.z = qv.z + (oa[mt][2] + cob[(mt*4+2)*256 + ci]) * linv;
      st.w = qv.w + (oa[mt][3] + cob[(mt*4+3)*256 + ci]) * linv;
      *(float4*)(op + dbase) = st;
    }
  }
}

// ---------------------------------------------------------------------------
// fused_out (validated, byte-identical): LN0 + res+relu(GEMM Wo) + LN1.
// ---------------------------------------------------------------------------
__global__ __launch_bounds__(512) void fused_out(
    const float* __restrict__ x, const float* __restrict__ Wo,
    const float* __restrict__ bo,
    const float* __restrict__ g0v, const float* __restrict__ b0v,
    const float* __restrict__ g1v, const float* __restrict__ b1v,
    float* __restrict__ y)
{
  __shared__ __align__(16) unsigned short As[32][256];
  __shared__ __align__(16) unsigned short Ws[256][64];
  __shared__ float mu_[32], rs_[32];
  float* P = (float*)&Ws[0][0];

  const int tid = threadIdx.x;
  const int w = tid >> 6, lane = tid & 63;
  const int l15 = lane & 15, g = lane >> 4;
  const int r0 = blockIdx.x * 32;

  {
    float4 g4 = *(const float4*)(g0v + lane*4);
    float4 b4 = *(const float4*)(b0v + lane*4);
    #pragma unroll
    for (int rr = 0; rr < 4; ++rr) {
      int m = w*4 + rr;
      const float* xr = x + (size_t)(r0 + m) * 256;
      float4 v = *(const float4*)(xr + lane*4);
      float s = v.x + v.y + v.z + v.w;
      #pragma unroll
      for (int mk = 1; mk <= 32; mk <<= 1) s += __shfl_xor(s, mk, 64);
      float mu = s * (1.0f/256.0f);
      float dx = v.x-mu, dy = v.y-mu, dz = v.z-mu, dw = v.w-mu;
      float qq = dx*dx + dy*dy + dz*dz + dw*dw;
      #pragma unroll
      for (int mk = 1; mk <= 32; mk <<= 1) qq += __shfl_xor(qq, mk, 64);
      float rstd = rsqrtf(qq * (1.0f/256.0f) + 1e-5f);
      if (lane == 0) { mu_[m] = mu; rs_[m] = rstd; }
      float nx = dx*rstd*g4.x + b4.x;
      float ny = dy*rstd*g4.y + b4.y;
      float nz = dz*rstd*g4.z + b4.z;
      float nw = dw*rstd*g4.w + b4.w;
      int2 pv = { pk2(nx, ny), pk2(nz, nw) };
      *(int2*)&As[m][SWZ(m, lane*4)] = pv;
    }
  }
  __syncthreads();

  const int m0 = (w >> 2) * 16;
  const int e0 = (w & 3) * 64;
  f32x4 acc4[4];
  #pragma unroll
  for (int j = 0; j < 4; ++j)
    #pragma unroll
    for (int r = 0; r < 4; ++r) acc4[j][r] = 0.f;

  for (int k0 = 0; k0 < 256; k0 += 64) {
    if (k0) __syncthreads();
    {
      const int ch = tid & 7;
      const int er = tid >> 3;
      #pragma unroll
      for (int p = 0; p < 4; ++p) {
        int e = p*64 + er;
        const float* wp = Wo + (size_t)e*256 + k0 + ch*8;
        float4 u0 = *(const float4*)wp;
        float4 u1 = *(const float4*)(wp + 4);
        int4 pk = { pk2(u0.x,u0.y), pk2(u0.z,u0.w), pk2(u1.x,u1.y), pk2(u1.z,u1.w) };
        *(int4*)&Ws[e][SWZ(e, ch*8)] = pk;
      }
    }
    __syncthreads();
    __builtin_amdgcn_s_setprio(1);
    #pragma unroll
    for (int ds_ = 0; ds_ < 2; ++ds_) {
      int ma = m0 + l15;
      bf16x8 af = *(const bf16x8*)&As[ma][SWZ(ma, k0 + ds_*32 + g*8)];
      #pragma unroll
      for (int j = 0; j < 4; ++j) {
        int er = e0 + j*16 + l15;
        bf16x8 bfv = *(const bf16x8*)&Ws[er][SWZ(er, ds_*32 + g*8)];
        acc4[j] = __builtin_amdgcn_mfma_f32_16x16x32_bf16(af, bfv, acc4[j], 0, 0, 0);
      }
    }
    __builtin_amdgcn_s_setprio(0);
  }
  __syncthreads();

  #pragma unroll
  for (int j = 0; j < 4; ++j) {
    int e = e0 + j*16 + l15;
    float bov = bo[e], g0e = g0v[e], b0e = b0v[e];
    #pragma unroll
    for (int r = 0; r < 4; ++r) {
      int m = m0 + g*4 + r;
      float xv = x[(size_t)(r0 + m)*256 + e];
      float resv = (xv - mu_[m]) * rs_[m] * g0e + b0e;
      float val = acc4[j][r] + bov;
      P[m*256 + e] = resv + fmaxf(val, 0.f);
    }
  }
  __syncthreads();

  {
    float4 g4 = *(const float4*)(g1v + lane*4);
    float4 b4 = *(const float4*)(b1v + lane*4);
    #pragma unroll
    for (int rr = 0; rr < 4; ++rr) {
      int m = w*4 + rr;
      float4 v = *(const float4*)&P[m*256 + lane*4];
      float s = v.x + v.y + v.z + v.w;
      #pragma unroll
      for (int mk = 1; mk <= 32; mk <<= 1) s += __shfl_xor(s, mk, 64);
      float mu = s * (1.0f/256.0f);
      float dx = v.x-mu, dy = v.y-mu, dz = v.z-mu, dw = v.w-mu;
      float qq = dx*dx + dy*dy + dz*dz + dw*dw;
      #pragma unroll
      for (int mk = 1; mk <= 32; mk <<= 1) qq += __shfl_xor(qq, mk, 64);
      float rstd = rsqrtf(qq * (1.0f/256.0f) + 1e-5f);
      float4 o;
      o.x = dx*rstd*g4.x + b4.x; o.y = dy*rstd*g4.y + b4.y;
      o.z = dz*rstd*g4.z + b4.z; o.w = dw*rstd*g4.w + b4.w;
      *(float4*)(y + (size_t)(r0 + m)*256 + lane*4) = o;
    }
  }
}

// ---------------------------------------------------------------------------
extern "C" void kernel_launch(void* const* d_in, const int* in_sizes, int n_in,
                              void* d_out, int out_size, void* d_ws, size_t ws_size,
                              hipStream_t stream) {
  const float* Q  = (const float*)d_in[0];
  const float* K  = (const float*)d_in[1];
  const float* Wq = (const float*)d_in[2];
  const float* bq = (const float*)d_in[3];
  const float* Wk = (const float*)d_in[4];
  const float* bk = (const float*)d_in[5];
  const float* Wv = (const float*)d_in[6];
  const float* bv = (const float*)d_in[7];
  const float* Wo = (const float*)d_in[8];
  const float* bo = (const float*)d_in[9];
  const float* g0 = (const float*)d_in[10];
  const float* b0 = (const float*)d_in[11];
  const float* g1 = (const float*)d_in[12];
  const float* b1 = (const float*)d_in[13];
  float* out = (float*)d_out;

  const size_t SZ = (size_t)4 * 2048 * 256;
  if (ws_size < 2 * SZ * sizeof(unsigned short)) return;  // need 8 MB

  unsigned short* kbf = (unsigned short*)d_ws;
  unsigned short* vtb = kbf + SZ;

  const int ATTN_LDS = 65536;
  hipFuncSetAttribute((const void*)attn_mfma10,
                      hipFuncAttributeMaxDynamicSharedMemorySize, ATTN_LDS);

  proj2_kernel<<<dim3(2, 128, 3), dim3(256), 0, stream>>>(
      Q, K, Wq, bq, Wk, bk, Wv, bv, out, kbf, vtb);
  attn_mfma10<<<dim3(512), dim3(512), ATTN_LDS, stream>>>(out, kbf, vtb, out);
  fused_out<<<dim3(256), dim3(512), 0, stream>>>(out, Wo, bo, g0, b0, g1, b1, out);
}